// Round 2
// baseline (26271.158 us; speedup 1.0000x reference)
//
#include <hip/hip_runtime.h>
#include <hip/hip_bf16.h>

#define BB 512     // batch
#define TT 96      // encoder steps
#define PP 96      // decoder steps
#define EE 321     // input features
#define CC 321     // output channels
#define HH 512     // hidden
#define G4 2048    // 4*H
#define EPAD 352   // 321 padded to multiple of 32

// ---------- one-time (per launch) weight pad-copy fp32 -> padded fp32 ----------
__global__ void cvt_mat(const float* __restrict__ src, float* __restrict__ dst,
                        int rows, int cols, int rowspad, int colspad){
  int total = rowspad * colspad;
  for (int idx = blockIdx.x * blockDim.x + threadIdx.x; idx < total; idx += gridDim.x * blockDim.x){
    int r = idx / colspad, cc = idx - r * colspad;
    dst[idx] = (r < rows && cc < cols) ? src[r * cols + cc] : 0.f;
  }
}

__global__ void cvt_bias(const float* __restrict__ b1, const float* __restrict__ b2,
                         float* __restrict__ dst, int n, int npad){
  for (int i = blockIdx.x * blockDim.x + threadIdx.x; i < npad; i += gridDim.x * blockDim.x){
    float v = 0.f;
    if (i < n){ v = b1[i]; if (b2) v += b2[i]; }
    dst[i] = v;
  }
}

// inp[b][j] = x_enc[b, T-1, j] (fp32), pad cols zeroed
__global__ void init_inp(const float* __restrict__ x_enc, float* __restrict__ inp){
  int total = BB * EPAD;
  for (int idx = blockIdx.x * blockDim.x + threadIdx.x; idx < total; idx += gridDim.x * blockDim.x){
    int b = idx / EPAD, j = idx - b * EPAD;
    inp[idx] = (j < EE) ? x_enc[(long)b * TT * EE + (long)(TT - 1) * EE + j] : 0.f;
  }
}

// ---------- fused LSTM cell step: gates = X@Wih^T + hprev@Whh^T + bias; cell update ----------
// grid (16,16): blockIdx.x = batch tile (32 rows), blockIdx.y = unit tile (32 hidden units, all 4 gates)
// block 512 threads: tx = unit lane (0..31), ty = 0..15 -> 2 batch rows each
__global__ __launch_bounds__(512) void lstm_step(
    const float* __restrict__ Xf,    // padded, aligned input (or null)
    const float* __restrict__ Xg,    // guarded strided input (raw x_enc) (or null)
    long xstride,
    int K1, int K1pad,
    const float* __restrict__ Wih,   // [2048][K1pad] fp32
    const float* __restrict__ Whh,   // [2048][512]   fp32
    const float* __restrict__ bias,  // [2048] fp32 (bih+bhh)
    const float* __restrict__ hprev, // [512][512] fp32
    float* __restrict__ hnext,       // [512][512] fp32
    float* __restrict__ cst)         // [512][512] fp32 in/out
{
  __shared__ float Xl[32][36];
  __shared__ float Wl[128][36];
  const int tid = threadIdx.x;
  const int tx = tid & 31;
  const int ty = tid >> 5;           // 0..15
  const int b0 = blockIdx.x * 32;
  const int u0 = blockIdx.y * 32;

  float acc[2][4];
  #pragma unroll
  for (int r = 0; r < 2; ++r)
    #pragma unroll
    for (int g = 0; g < 4; ++g) acc[r][g] = 0.f;

  // staging index maps
  const int xr = tid >> 4;           // 0..31  (X row)
  const int xk = (tid & 15) * 2;     // 0,2,..30
  const int wr = tid >> 2;           // 0..127 (W row: gate*32+unit)
  const int wk = (tid & 3) * 8;      // 0,8,16,24
  const int wgrow = (wr >> 5) * HH + u0 + (wr & 31);  // global weight row

  // ---- phase 1: X @ Wih^T ----
  {
    const int nch = K1pad >> 5;
    for (int ch = 0; ch < nch; ++ch){
      const int k0 = ch << 5;
      if (Xg){
        const long base = (long)(b0 + xr) * xstride + k0 + xk;
        Xl[xr][xk]     = (k0 + xk     < K1) ? Xg[base]     : 0.f;
        Xl[xr][xk + 1] = (k0 + xk + 1 < K1) ? Xg[base + 1] : 0.f;
      } else {
        const float2 v = *(const float2*)(Xf + (long)(b0 + xr) * xstride + k0 + xk);
        Xl[xr][xk] = v.x; Xl[xr][xk + 1] = v.y;
      }
      {
        const float* src = Wih + (long)wgrow * K1pad + k0 + wk;
        *(float4*)&Wl[wr][wk]     = *(const float4*)(src);
        *(float4*)&Wl[wr][wk + 4] = *(const float4*)(src + 4);
      }
      __syncthreads();
      #pragma unroll
      for (int kk = 0; kk < 32; kk += 4){
        float4 xa0 = *(const float4*)&Xl[2 * ty][kk];
        float4 xa1 = *(const float4*)&Xl[2 * ty + 1][kk];
        #pragma unroll
        for (int g = 0; g < 4; ++g){
          float4 wv = *(const float4*)&Wl[g * 32 + tx][kk];
          acc[0][g] += xa0.x * wv.x + xa0.y * wv.y + xa0.z * wv.z + xa0.w * wv.w;
          acc[1][g] += xa1.x * wv.x + xa1.y * wv.y + xa1.z * wv.z + xa1.w * wv.w;
        }
      }
      __syncthreads();
    }
  }
  // ---- phase 2: hprev @ Whh^T (K = 512) ----
  {
    for (int ch = 0; ch < 16; ++ch){
      const int k0 = ch << 5;
      {
        const float2 v = *(const float2*)(hprev + (long)(b0 + xr) * HH + k0 + xk);
        Xl[xr][xk] = v.x; Xl[xr][xk + 1] = v.y;
      }
      {
        const float* src = Whh + (long)wgrow * HH + k0 + wk;
        *(float4*)&Wl[wr][wk]     = *(const float4*)(src);
        *(float4*)&Wl[wr][wk + 4] = *(const float4*)(src + 4);
      }
      __syncthreads();
      #pragma unroll
      for (int kk = 0; kk < 32; kk += 4){
        float4 xa0 = *(const float4*)&Xl[2 * ty][kk];
        float4 xa1 = *(const float4*)&Xl[2 * ty + 1][kk];
        #pragma unroll
        for (int g = 0; g < 4; ++g){
          float4 wv = *(const float4*)&Wl[g * 32 + tx][kk];
          acc[0][g] += xa0.x * wv.x + xa0.y * wv.y + xa0.z * wv.z + xa0.w * wv.w;
          acc[1][g] += xa1.x * wv.x + xa1.y * wv.y + xa1.z * wv.z + xa1.w * wv.w;
        }
      }
      __syncthreads();
    }
  }
  // ---- epilogue: LSTM cell ----
  const int j = u0 + tx;
  #pragma unroll
  for (int r = 0; r < 2; ++r){
    const int b = b0 + 2 * ty + r;
    const long sidx = (long)b * HH + j;
    float gi = acc[r][0] + bias[j];
    float gf = acc[r][1] + bias[HH + j];
    float gg = acc[r][2] + bias[2 * HH + j];
    float go = acc[r][3] + bias[3 * HH + j];
    float si = 1.f / (1.f + expf(-gi));
    float sf = 1.f / (1.f + expf(-gf));
    float so = 1.f / (1.f + expf(-go));
    float cn = sf * cst[sidx] + si * tanhf(gg);
    float hn = so * tanhf(cn);
    cst[sidx]   = cn;
    hnext[sidx] = hn;
  }
}

// ---------- FC head: out = h1 @ fcW^T + fcb; writes fp32 d_out slice + fp32 feedback ----------
// grid (11,16): blockIdx.x = m tile (32 of 352), blockIdx.y = batch tile (32)
__global__ __launch_bounds__(256) void fc_step(
    const float* __restrict__ h1,   // [512][512]
    const float* __restrict__ Wfc,  // [352][512] fp32 (rows >=321 zero)
    const float* __restrict__ bfc,  // [352]
    float* __restrict__ out, float* __restrict__ inp, int p)
{
  __shared__ float Hl[32][36];
  __shared__ float Fl[32][36];
  const int tid = threadIdx.x;
  const int tx = tid & 31;           // m lane
  const int ty = tid >> 5;           // 0..7 -> 4 rows each
  const int m0 = blockIdx.x * 32;
  const int b0 = blockIdx.y * 32;

  float acc[4] = {0.f, 0.f, 0.f, 0.f};
  const int sr = tid >> 3;           // 0..31
  const int sk = (tid & 7) * 4;      // 0,4,..28

  for (int ch = 0; ch < 16; ++ch){
    const int k0 = ch << 5;
    *(float4*)&Hl[sr][sk] = *(const float4*)(h1  + (long)(b0 + sr) * HH + k0 + sk);
    *(float4*)&Fl[sr][sk] = *(const float4*)(Wfc + (long)(m0 + sr) * HH + k0 + sk);
    __syncthreads();
    #pragma unroll
    for (int kk = 0; kk < 32; kk += 4){
      float4 wv = *(const float4*)&Fl[tx][kk];
      #pragma unroll
      for (int r = 0; r < 4; ++r){
        float4 hv = *(const float4*)&Hl[ty * 4 + r][kk];
        acc[r] += hv.x * wv.x + hv.y * wv.y + hv.z * wv.z + hv.w * wv.w;
      }
    }
    __syncthreads();
  }
  const int m = m0 + tx;
  if (m < CC){
    #pragma unroll
    for (int r = 0; r < 4; ++r){
      const int b = b0 + ty * 4 + r;
      float v = acc[r] + bfc[m];
      out[(long)b * PP * CC + (long)p * CC + m] = v;
      inp[(long)b * EPAD + m] = v;
    }
  }
}

extern "C" void kernel_launch(void* const* d_in, const int* in_sizes, int n_in,
                              void* d_out, int out_size, void* d_ws, size_t ws_size,
                              hipStream_t stream) {
  const float* x_enc  = (const float*)d_in[0];
  const float* e_Wih0 = (const float*)d_in[4];
  const float* e_Whh0 = (const float*)d_in[5];
  const float* e_bih0 = (const float*)d_in[6];
  const float* e_bhh0 = (const float*)d_in[7];
  const float* e_Wih1 = (const float*)d_in[8];
  const float* e_Whh1 = (const float*)d_in[9];
  const float* e_bih1 = (const float*)d_in[10];
  const float* e_bhh1 = (const float*)d_in[11];
  const float* d_Wih0 = (const float*)d_in[12];
  const float* d_Whh0 = (const float*)d_in[13];
  const float* d_bih0 = (const float*)d_in[14];
  const float* d_bhh0 = (const float*)d_in[15];
  const float* d_Wih1 = (const float*)d_in[16];
  const float* d_Whh1 = (const float*)d_in[17];
  const float* d_bih1 = (const float*)d_in[18];
  const float* d_bhh1 = (const float*)d_in[19];
  const float* fc_W   = (const float*)d_in[20];
  const float* fc_b   = (const float*)d_in[21];

  float* ws = (float*)d_ws;
  size_t off = 0;
  auto alloc = [&](size_t n){ float* pp = ws + off; off += n; return pp; };
  float* We0ih = alloc((size_t)G4 * EPAD);
  float* We0hh = alloc((size_t)G4 * HH);
  float* We1ih = alloc((size_t)G4 * HH);
  float* We1hh = alloc((size_t)G4 * HH);
  float* Wd0ih = alloc((size_t)G4 * EPAD);
  float* Wd0hh = alloc((size_t)G4 * HH);
  float* Wd1ih = alloc((size_t)G4 * HH);
  float* Wd1hh = alloc((size_t)G4 * HH);
  float* Wfc   = alloc((size_t)EPAD * HH);
  float* be0   = alloc(G4);
  float* be1   = alloc(G4);
  float* bd0   = alloc(G4);
  float* bd1   = alloc(G4);
  float* bfc   = alloc(EPAD);
  // states: h0A,h1A,c0,c1 contiguous for one memset
  float* h0A = alloc((size_t)BB * HH);
  float* h1A = alloc((size_t)BB * HH);
  float* c0  = alloc((size_t)BB * HH);
  float* c1  = alloc((size_t)BB * HH);
  float* h0B = alloc((size_t)BB * HH);
  float* h1B = alloc((size_t)BB * HH);
  float* inp = alloc((size_t)BB * EPAD);

  // weight/bias prep (every launch; ws is re-poisoned by the harness)
  cvt_mat<<<512, 256, 0, stream>>>(e_Wih0, We0ih, G4, EE, G4, EPAD);
  cvt_mat<<<512, 256, 0, stream>>>(e_Whh0, We0hh, G4, HH, G4, HH);
  cvt_mat<<<512, 256, 0, stream>>>(e_Wih1, We1ih, G4, HH, G4, HH);
  cvt_mat<<<512, 256, 0, stream>>>(e_Whh1, We1hh, G4, HH, G4, HH);
  cvt_mat<<<512, 256, 0, stream>>>(d_Wih0, Wd0ih, G4, EE, G4, EPAD);
  cvt_mat<<<512, 256, 0, stream>>>(d_Whh0, Wd0hh, G4, HH, G4, HH);
  cvt_mat<<<512, 256, 0, stream>>>(d_Wih1, Wd1ih, G4, HH, G4, HH);
  cvt_mat<<<512, 256, 0, stream>>>(d_Whh1, Wd1hh, G4, HH, G4, HH);
  cvt_mat<<<512, 256, 0, stream>>>(fc_W,   Wfc,   CC, HH, EPAD, HH);
  cvt_bias<<<8, 256, 0, stream>>>(e_bih0, e_bhh0, be0, G4, G4);
  cvt_bias<<<8, 256, 0, stream>>>(e_bih1, e_bhh1, be1, G4, G4);
  cvt_bias<<<8, 256, 0, stream>>>(d_bih0, d_bhh0, bd0, G4, G4);
  cvt_bias<<<8, 256, 0, stream>>>(d_bih1, d_bhh1, bd1, G4, G4);
  cvt_bias<<<2, 256, 0, stream>>>(fc_b, nullptr, bfc, CC, EPAD);
  hipMemsetAsync(h0A, 0, (size_t)4 * BB * HH * sizeof(float), stream); // h0A,h1A,c0,c1
  init_inp<<<512, 256, 0, stream>>>(x_enc, inp);

  float* h0c = h0A; float* h0n = h0B;
  float* h1c = h1A; float* h1n = h1B;

  // encoder: layer0 and layer1 lockstep (layer1 step t consumes layer0's fresh h)
  for (int t = 0; t < TT; ++t){
    lstm_step<<<dim3(16, 16), 512, 0, stream>>>(
        nullptr, x_enc + (long)t * EE, (long)TT * EE, EE, EPAD,
        We0ih, We0hh, be0, h0c, h0n, c0);
    lstm_step<<<dim3(16, 16), 512, 0, stream>>>(
        h0n, nullptr, HH, HH, HH,
        We1ih, We1hh, be1, h1c, h1n, c1);
    float* t0 = h0c; h0c = h0n; h0n = t0;
    float* t1 = h1c; h1c = h1n; h1n = t1;
  }

  // decoder: states carry over from encoder (layer0 state -> dec cell0, layer1 -> dec cell1)
  float* out = (float*)d_out;
  for (int p = 0; p < PP; ++p){
    lstm_step<<<dim3(16, 16), 512, 0, stream>>>(
        inp, nullptr, EPAD, EE, EPAD,
        Wd0ih, Wd0hh, bd0, h0c, h0n, c0);
    lstm_step<<<dim3(16, 16), 512, 0, stream>>>(
        h0n, nullptr, HH, HH, HH,
        Wd1ih, Wd1hh, bd1, h1c, h1n, c1);
    fc_step<<<dim3(11, 16), 256, 0, stream>>>(h1n, Wfc, bfc, out, inp, p);
    float* t0 = h0c; h0c = h0n; h0n = t0;
    float* t1 = h1c; h1c = h1n; h1n = t1;
  }
}

// Round 3
// 17836.012 us; speedup vs baseline: 1.4729x; 1.4729x over previous
//
#include <hip/hip_runtime.h>
#include <hip/hip_bf16.h>

#define BB 512     // batch
#define TT 96      // encoder steps
#define PP 96      // decoder steps
#define EE 321     // input features
#define CC 321     // output channels
#define HH 512     // hidden
#define G4 2048    // 4*H
#define EPAD 352   // 321 padded to multiple of 32

typedef __attribute__((ext_vector_type(8))) short bf16x8;
typedef __attribute__((ext_vector_type(4))) float floatx4;
typedef __attribute__((ext_vector_type(4))) unsigned short ushort4v;

__device__ __forceinline__ void splitf(float v, unsigned short& h, unsigned short& l){
  __hip_bfloat16 bh = __float2bfloat16(v);
  h = *reinterpret_cast<unsigned short*>(&bh);
  float r = v - __bfloat162float(bh);
  __hip_bfloat16 bl = __float2bfloat16(r);
  l = *reinterpret_cast<unsigned short*>(&bl);
}

// ---------- prep: split fp32 weight [rows][cols] -> bf16 hi/lo [rows][colspad] ----------
__global__ void cvt_mat_split(const float* __restrict__ src, unsigned short* __restrict__ hi,
                              unsigned short* __restrict__ lo, int rows, int cols, int colspad){
  int total = rows * colspad;
  for (int idx = blockIdx.x * blockDim.x + threadIdx.x; idx < total; idx += gridDim.x * blockDim.x){
    int r = idx / colspad, cc = idx - r * colspad;
    float v = (cc < cols) ? src[(size_t)r * cols + cc] : 0.f;
    unsigned short h, l; splitf(v, h, l);
    hi[idx] = h; lo[idx] = l;
  }
}

// fp32 pad-copy (FC weight)
__global__ void cvt_mat(const float* __restrict__ src, float* __restrict__ dst,
                        int rows, int cols, int rowspad, int colspad){
  int total = rowspad * colspad;
  for (int idx = blockIdx.x * blockDim.x + threadIdx.x; idx < total; idx += gridDim.x * blockDim.x){
    int r = idx / colspad, cc = idx - r * colspad;
    dst[idx] = (r < rows && cc < cols) ? src[(size_t)r * cols + cc] : 0.f;
  }
}

__global__ void cvt_bias(const float* __restrict__ b1, const float* __restrict__ b2,
                         float* __restrict__ dst, int n, int npad){
  for (int i = blockIdx.x * blockDim.x + threadIdx.x; i < npad; i += gridDim.x * blockDim.x){
    float v = 0.f;
    if (i < n){ v = b1[i]; if (b2) v += b2[i]; }
    dst[i] = v;
  }
}

// inp[b][j] = x_enc[b, T-1, j] (fp32), pad cols zeroed
__global__ void init_inp(const float* __restrict__ x_enc, float* __restrict__ inp){
  int total = BB * EPAD;
  for (int idx = blockIdx.x * blockDim.x + threadIdx.x; idx < total; idx += gridDim.x * blockDim.x){
    int b = idx / EPAD, j = idx - b * EPAD;
    inp[idx] = (j < EE) ? x_enc[(size_t)b * TT * EE + (size_t)(TT - 1) * EE + j] : 0.f;
  }
}

// ---------- MFMA LSTM cell step ----------
// gates[b][g*512+u] = X@Wih^T + hprev@Whh^T + bias, then cell update.
// Split-bf16: P ~= Xh@Wh + Xh@Wl + Xl@Wh  (3 MFMAs per tile).
// grid (16,16): x = batch tile (32), y = unit tile (32). block 256 thr = 4 waves, wave w = gate w.
// Each wave: 32(M)x32(N) via 2x2 grid of 16x16x32 MFMAs per 32-K chunk.
__global__ __launch_bounds__(256) void lstm_mfma(
    const float* __restrict__ Xf,    // padded aligned fp32 input (or null)
    const float* __restrict__ Xg,    // guarded strided fp32 input (raw x_enc) (or null)
    long xstride, int K1, int K1pad,
    const unsigned short* __restrict__ Wih_h, const unsigned short* __restrict__ Wih_l, // [2048][K1pad]
    const unsigned short* __restrict__ Whh_h, const unsigned short* __restrict__ Whh_l, // [2048][512]
    const float* __restrict__ bias,  // [2048]
    const float* __restrict__ hprev, // [512][512]
    float* __restrict__ hnext,       // [512][512]
    float* __restrict__ cst)         // [512][512]
{
  __shared__ unsigned short sXh[32][40], sXl[32][40];    // +8 pad: 80B row stride
  __shared__ unsigned short sWh[128][40], sWl[128][40];
  __shared__ float sG[4][32][33];

  const int tid  = threadIdx.x;
  const int lane = tid & 63;
  const int wid  = tid >> 6;         // 0..3 = gate
  const int m0 = blockIdx.x * 32;
  const int u0 = blockIdx.y * 32;

  floatx4 acc00 = {0.f,0.f,0.f,0.f}, acc01 = acc00, acc10 = acc00, acc11 = acc00;

  const int xr = tid >> 3;           // 0..31 (X stage row)
  const int kc = (tid & 7) * 4;      // 0..28 (X stage k)
  const int wr = tid >> 1;           // 0..127 (W stage row: gate*32+unit)
  const int ks = (tid & 1) * 16;     // 0 or 16
  const size_t wgrow = (size_t)((wr >> 5) * HH + u0 + (wr & 31));

  const int mrow = lane & 15;
  const int quad = lane >> 4;

  const int nch1 = K1pad >> 5;
  const int ncht = nch1 + (HH >> 5);

  for (int ch = 0; ch < ncht; ++ch){
    const bool ph1 = ch < nch1;
    const int k0 = (ph1 ? ch : ch - nch1) << 5;

    // ---- stage X (32 x 32 fp32 -> bf16 hi/lo) ----
    {
      float x0, x1, x2, x3;
      if (ph1){
        if (Xg){
          const float* src = Xg + (size_t)(m0 + xr) * xstride + k0 + kc;
          x0 = (k0 + kc + 0 < K1) ? src[0] : 0.f;
          x1 = (k0 + kc + 1 < K1) ? src[1] : 0.f;
          x2 = (k0 + kc + 2 < K1) ? src[2] : 0.f;
          x3 = (k0 + kc + 3 < K1) ? src[3] : 0.f;
        } else {
          float4 v = *(const float4*)(Xf + (size_t)(m0 + xr) * xstride + k0 + kc);
          x0 = v.x; x1 = v.y; x2 = v.z; x3 = v.w;
        }
      } else {
        float4 v = *(const float4*)(hprev + (size_t)(m0 + xr) * HH + k0 + kc);
        x0 = v.x; x1 = v.y; x2 = v.z; x3 = v.w;
      }
      ushort4v hh, ll;
      splitf(x0, ((unsigned short*)&hh)[0], ((unsigned short*)&ll)[0]);
      splitf(x1, ((unsigned short*)&hh)[1], ((unsigned short*)&ll)[1]);
      splitf(x2, ((unsigned short*)&hh)[2], ((unsigned short*)&ll)[2]);
      splitf(x3, ((unsigned short*)&hh)[3], ((unsigned short*)&ll)[3]);
      *(ushort4v*)&sXh[xr][kc] = hh;
      *(ushort4v*)&sXl[xr][kc] = ll;
    }
    // ---- stage W (128 rows x 32 k, hi+lo pure copy) ----
    {
      const unsigned short* Wh = ph1 ? Wih_h : Whh_h;
      const unsigned short* Wl = ph1 ? Wih_l : Whh_l;
      const size_t Kp = ph1 ? (size_t)K1pad : (size_t)HH;
      const unsigned short* sh = Wh + wgrow * Kp + k0 + ks;
      const unsigned short* sl = Wl + wgrow * Kp + k0 + ks;
      *(bf16x8*)&sWh[wr][ks]     = *(const bf16x8*)(sh);
      *(bf16x8*)&sWh[wr][ks + 8] = *(const bf16x8*)(sh + 8);
      *(bf16x8*)&sWl[wr][ks]     = *(const bf16x8*)(sl);
      *(bf16x8*)&sWl[wr][ks + 8] = *(const bf16x8*)(sl + 8);
    }
    __syncthreads();
    // ---- compute: 12 MFMAs ----
    {
      bf16x8 ah0 = *(const bf16x8*)&sXh[mrow][quad * 8];
      bf16x8 ah1 = *(const bf16x8*)&sXh[16 + mrow][quad * 8];
      bf16x8 al0 = *(const bf16x8*)&sXl[mrow][quad * 8];
      bf16x8 al1 = *(const bf16x8*)&sXl[16 + mrow][quad * 8];
      const int wb = wid * 32;
      bf16x8 bh0 = *(const bf16x8*)&sWh[wb + mrow][quad * 8];
      bf16x8 bh1 = *(const bf16x8*)&sWh[wb + 16 + mrow][quad * 8];
      bf16x8 bl0 = *(const bf16x8*)&sWl[wb + mrow][quad * 8];
      bf16x8 bl1 = *(const bf16x8*)&sWl[wb + 16 + mrow][quad * 8];
      acc00 = __builtin_amdgcn_mfma_f32_16x16x32_bf16(ah0, bh0, acc00, 0, 0, 0);
      acc00 = __builtin_amdgcn_mfma_f32_16x16x32_bf16(ah0, bl0, acc00, 0, 0, 0);
      acc00 = __builtin_amdgcn_mfma_f32_16x16x32_bf16(al0, bh0, acc00, 0, 0, 0);
      acc01 = __builtin_amdgcn_mfma_f32_16x16x32_bf16(ah0, bh1, acc01, 0, 0, 0);
      acc01 = __builtin_amdgcn_mfma_f32_16x16x32_bf16(ah0, bl1, acc01, 0, 0, 0);
      acc01 = __builtin_amdgcn_mfma_f32_16x16x32_bf16(al0, bh1, acc01, 0, 0, 0);
      acc10 = __builtin_amdgcn_mfma_f32_16x16x32_bf16(ah1, bh0, acc10, 0, 0, 0);
      acc10 = __builtin_amdgcn_mfma_f32_16x16x32_bf16(ah1, bl0, acc10, 0, 0, 0);
      acc10 = __builtin_amdgcn_mfma_f32_16x16x32_bf16(al1, bh0, acc10, 0, 0, 0);
      acc11 = __builtin_amdgcn_mfma_f32_16x16x32_bf16(ah1, bh1, acc11, 0, 0, 0);
      acc11 = __builtin_amdgcn_mfma_f32_16x16x32_bf16(ah1, bl1, acc11, 0, 0, 0);
      acc11 = __builtin_amdgcn_mfma_f32_16x16x32_bf16(al1, bh1, acc11, 0, 0, 0);
    }
    __syncthreads();
  }

  // ---- epilogue: exchange gates via LDS, cell update ----
  #pragma unroll
  for (int r = 0; r < 4; ++r){
    sG[wid][0  + quad * 4 + r][0  + mrow] = acc00[r];
    sG[wid][0  + quad * 4 + r][16 + mrow] = acc01[r];
    sG[wid][16 + quad * 4 + r][0  + mrow] = acc10[r];
    sG[wid][16 + quad * 4 + r][16 + mrow] = acc11[r];
  }
  __syncthreads();
  for (int c = tid; c < 1024; c += 256){
    const int m = c >> 5, u = c & 31;
    const float gi = sG[0][m][u] + bias[u0 + u];
    const float gf = sG[1][m][u] + bias[HH + u0 + u];
    const float gg = sG[2][m][u] + bias[2 * HH + u0 + u];
    const float go = sG[3][m][u] + bias[3 * HH + u0 + u];
    const float si = 1.f / (1.f + expf(-gi));
    const float sf = 1.f / (1.f + expf(-gf));
    const float so = 1.f / (1.f + expf(-go));
    const size_t sidx = (size_t)(m0 + m) * HH + u0 + u;
    const float cn = sf * cst[sidx] + si * tanhf(gg);
    const float hn = so * tanhf(cn);
    cst[sidx]   = cn;
    hnext[sidx] = hn;
  }
}

// ---------- FC head (fp32): out = h1 @ fcW^T + fcb; writes d_out slice + feedback ----------
__global__ __launch_bounds__(256) void fc_step(
    const float* __restrict__ h1,   // [512][512]
    const float* __restrict__ Wfc,  // [352][512] (rows >=321 zero)
    const float* __restrict__ bfc,  // [352]
    float* __restrict__ out, float* __restrict__ inp, int p)
{
  __shared__ float Hl[32][36];
  __shared__ float Fl[32][36];
  const int tid = threadIdx.x;
  const int tx = tid & 31;
  const int ty = tid >> 5;
  const int m0 = blockIdx.x * 32;
  const int b0 = blockIdx.y * 32;

  float acc[4] = {0.f, 0.f, 0.f, 0.f};
  const int sr = tid >> 3;
  const int sk = (tid & 7) * 4;

  for (int ch = 0; ch < 16; ++ch){
    const int k0 = ch << 5;
    *(float4*)&Hl[sr][sk] = *(const float4*)(h1  + (size_t)(b0 + sr) * HH + k0 + sk);
    *(float4*)&Fl[sr][sk] = *(const float4*)(Wfc + (size_t)(m0 + sr) * HH + k0 + sk);
    __syncthreads();
    #pragma unroll
    for (int kk = 0; kk < 32; kk += 4){
      float4 wv = *(const float4*)&Fl[tx][kk];
      #pragma unroll
      for (int r = 0; r < 4; ++r){
        float4 hv = *(const float4*)&Hl[ty * 4 + r][kk];
        acc[r] += hv.x * wv.x + hv.y * wv.y + hv.z * wv.z + hv.w * wv.w;
      }
    }
    __syncthreads();
  }
  const int m = m0 + tx;
  if (m < CC){
    #pragma unroll
    for (int r = 0; r < 4; ++r){
      const int b = b0 + ty * 4 + r;
      float v = acc[r] + bfc[m];
      out[(size_t)b * PP * CC + (size_t)p * CC + m] = v;
      inp[(size_t)b * EPAD + m] = v;
    }
  }
}

extern "C" void kernel_launch(void* const* d_in, const int* in_sizes, int n_in,
                              void* d_out, int out_size, void* d_ws, size_t ws_size,
                              hipStream_t stream) {
  const float* x_enc  = (const float*)d_in[0];
  const float* e_Wih0 = (const float*)d_in[4];
  const float* e_Whh0 = (const float*)d_in[5];
  const float* e_bih0 = (const float*)d_in[6];
  const float* e_bhh0 = (const float*)d_in[7];
  const float* e_Wih1 = (const float*)d_in[8];
  const float* e_Whh1 = (const float*)d_in[9];
  const float* e_bih1 = (const float*)d_in[10];
  const float* e_bhh1 = (const float*)d_in[11];
  const float* d_Wih0 = (const float*)d_in[12];
  const float* d_Whh0 = (const float*)d_in[13];
  const float* d_bih0 = (const float*)d_in[14];
  const float* d_bhh0 = (const float*)d_in[15];
  const float* d_Wih1 = (const float*)d_in[16];
  const float* d_Whh1 = (const float*)d_in[17];
  const float* d_bih1 = (const float*)d_in[18];
  const float* d_bhh1 = (const float*)d_in[19];
  const float* fc_W   = (const float*)d_in[20];
  const float* fc_b   = (const float*)d_in[21];

  char* base = (char*)d_ws;
  size_t off = 0;
  auto alloc_us = [&](size_t n){ unsigned short* p = (unsigned short*)(base + off); off += ((n * 2 + 15) & ~(size_t)15); return p; };
  auto alloc_f  = [&](size_t n){ float* p = (float*)(base + off); off += ((n * 4 + 15) & ~(size_t)15); return p; };

  unsigned short *We0ih_h = alloc_us((size_t)G4 * EPAD), *We0ih_l = alloc_us((size_t)G4 * EPAD);
  unsigned short *We0hh_h = alloc_us((size_t)G4 * HH),   *We0hh_l = alloc_us((size_t)G4 * HH);
  unsigned short *We1ih_h = alloc_us((size_t)G4 * HH),   *We1ih_l = alloc_us((size_t)G4 * HH);
  unsigned short *We1hh_h = alloc_us((size_t)G4 * HH),   *We1hh_l = alloc_us((size_t)G4 * HH);
  unsigned short *Wd0ih_h = alloc_us((size_t)G4 * EPAD), *Wd0ih_l = alloc_us((size_t)G4 * EPAD);
  unsigned short *Wd0hh_h = alloc_us((size_t)G4 * HH),   *Wd0hh_l = alloc_us((size_t)G4 * HH);
  unsigned short *Wd1ih_h = alloc_us((size_t)G4 * HH),   *Wd1ih_l = alloc_us((size_t)G4 * HH);
  unsigned short *Wd1hh_h = alloc_us((size_t)G4 * HH),   *Wd1hh_l = alloc_us((size_t)G4 * HH);
  float* Wfc = alloc_f((size_t)EPAD * HH);
  float* be0 = alloc_f(G4);
  float* be1 = alloc_f(G4);
  float* bd0 = alloc_f(G4);
  float* bd1 = alloc_f(G4);
  float* bfc = alloc_f(EPAD);
  float* h0A = alloc_f((size_t)BB * HH);
  float* h1A = alloc_f((size_t)BB * HH);
  float* c0  = alloc_f((size_t)BB * HH);
  float* c1  = alloc_f((size_t)BB * HH);
  float* h0B = alloc_f((size_t)BB * HH);
  float* h1B = alloc_f((size_t)BB * HH);
  float* inp = alloc_f((size_t)BB * EPAD);

  // prep (every launch; ws re-poisoned by harness)
  cvt_mat_split<<<512, 256, 0, stream>>>(e_Wih0, We0ih_h, We0ih_l, G4, EE, EPAD);
  cvt_mat_split<<<512, 256, 0, stream>>>(e_Whh0, We0hh_h, We0hh_l, G4, HH, HH);
  cvt_mat_split<<<512, 256, 0, stream>>>(e_Wih1, We1ih_h, We1ih_l, G4, HH, HH);
  cvt_mat_split<<<512, 256, 0, stream>>>(e_Whh1, We1hh_h, We1hh_l, G4, HH, HH);
  cvt_mat_split<<<512, 256, 0, stream>>>(d_Wih0, Wd0ih_h, Wd0ih_l, G4, EE, EPAD);
  cvt_mat_split<<<512, 256, 0, stream>>>(d_Whh0, Wd0hh_h, Wd0hh_l, G4, HH, HH);
  cvt_mat_split<<<512, 256, 0, stream>>>(d_Wih1, Wd1ih_h, Wd1ih_l, G4, HH, HH);
  cvt_mat_split<<<512, 256, 0, stream>>>(d_Whh1, Wd1hh_h, Wd1hh_l, G4, HH, HH);
  cvt_mat<<<512, 256, 0, stream>>>(fc_W, Wfc, CC, HH, EPAD, HH);
  cvt_bias<<<8, 256, 0, stream>>>(e_bih0, e_bhh0, be0, G4, G4);
  cvt_bias<<<8, 256, 0, stream>>>(e_bih1, e_bhh1, be1, G4, G4);
  cvt_bias<<<8, 256, 0, stream>>>(d_bih0, d_bhh0, bd0, G4, G4);
  cvt_bias<<<8, 256, 0, stream>>>(d_bih1, d_bhh1, bd1, G4, G4);
  cvt_bias<<<2, 256, 0, stream>>>(fc_b, nullptr, bfc, CC, EPAD);
  hipMemsetAsync(h0A, 0, (size_t)4 * BB * HH * sizeof(float), stream); // h0A,h1A,c0,c1
  init_inp<<<512, 256, 0, stream>>>(x_enc, inp);

  float* h0c = h0A; float* h0n = h0B;
  float* h1c = h1A; float* h1n = h1B;

  // encoder
  for (int t = 0; t < TT; ++t){
    lstm_mfma<<<dim3(16, 16), 256, 0, stream>>>(
        nullptr, x_enc + (size_t)t * EE, (long)TT * EE, EE, EPAD,
        We0ih_h, We0ih_l, We0hh_h, We0hh_l, be0, h0c, h0n, c0);
    lstm_mfma<<<dim3(16, 16), 256, 0, stream>>>(
        h0n, nullptr, HH, HH, HH,
        We1ih_h, We1ih_l, We1hh_h, We1hh_l, be1, h1c, h1n, c1);
    float* t0 = h0c; h0c = h0n; h0n = t0;
    float* t1 = h1c; h1c = h1n; h1n = t1;
  }

  // decoder
  float* out = (float*)d_out;
  for (int p = 0; p < PP; ++p){
    lstm_mfma<<<dim3(16, 16), 256, 0, stream>>>(
        inp, nullptr, EPAD, EE, EPAD,
        Wd0ih_h, Wd0ih_l, Wd0hh_h, Wd0hh_l, bd0, h0c, h0n, c0);
    lstm_mfma<<<dim3(16, 16), 256, 0, stream>>>(
        h0n, nullptr, HH, HH, HH,
        Wd1ih_h, Wd1ih_l, Wd1hh_h, Wd1hh_l, bd1, h1c, h1n, c1);
    fc_step<<<dim3(11, 16), 256, 0, stream>>>(h1n, Wfc, bfc, out, inp, p);
    float* t0 = h0c; h0c = h0n; h0n = t0;
    float* t1 = h1c; h1c = h1n; h1n = t1;
  }
}

// Round 5
// 13919.174 us; speedup vs baseline: 1.8874x; 1.2814x over previous
//
#include <hip/hip_runtime.h>
#include <hip/hip_bf16.h>

#define BB 512     // batch
#define TT 96      // encoder steps
#define PP 96      // decoder steps
#define EE 321     // input features
#define CC 321     // output channels
#define HH 512     // hidden
#define G4 2048    // 4*H
#define EPAD 352   // 321 padded to 32
#define NFC 384    // fc N pad (64-multiple)

#define LSTM_SMEM 36864  // bytes: sXh(12288)+sXl(12288)+sWh(6144)+sWl(6144); sG(34816) aliases base

typedef unsigned short u16;
typedef __attribute__((ext_vector_type(8))) short bf16x8;
typedef __attribute__((ext_vector_type(16))) float floatx16;

__device__ __forceinline__ void splitf(float v, u16& h, u16& l){
  __hip_bfloat16 bh = __float2bfloat16(v);
  h = *reinterpret_cast<u16*>(&bh);
  float r = v - __bfloat162float(bh);
  __hip_bfloat16 bl = __float2bfloat16(r);
  l = *reinterpret_cast<u16*>(&bl);
}

// ---------- prep: split fp32 [rows][cols] -> bf16 hi/lo [rowspad][colspad] ----------
__global__ void cvt_split(const float* __restrict__ src, u16* __restrict__ hi, u16* __restrict__ lo,
                          int rows, int cols, int rowspad, int colspad){
  int total = rowspad * colspad;
  for (int idx = blockIdx.x * blockDim.x + threadIdx.x; idx < total; idx += gridDim.x * blockDim.x){
    int r = idx / colspad, cc = idx - r * colspad;
    float v = (r < rows && cc < cols) ? src[(size_t)r * cols + cc] : 0.f;
    u16 h, l; splitf(v, h, l);
    hi[idx] = h; lo[idx] = l;
  }
}

__global__ void cvt_bias(const float* __restrict__ b1, const float* __restrict__ b2,
                         float* __restrict__ dst, int n, int npad){
  for (int i = blockIdx.x * blockDim.x + threadIdx.x; i < npad; i += gridDim.x * blockDim.x){
    float v = 0.f;
    if (i < n){ v = b1[i]; if (b2) v += b2[i]; }
    dst[i] = v;
  }
}

// inp split from x_enc[:, T-1, :], pad zeroed (pad stays zero: fc only writes n<CC)
__global__ void init_inp(const float* __restrict__ x_enc, u16* __restrict__ inph, u16* __restrict__ inpl){
  int total = BB * EPAD;
  for (int idx = blockIdx.x * blockDim.x + threadIdx.x; idx < total; idx += gridDim.x * blockDim.x){
    int b = idx / EPAD, j = idx - b * EPAD;
    float v = (j < EE) ? x_enc[(size_t)b * TT * EE + (size_t)(TT - 1) * EE + j] : 0.f;
    u16 h, l; splitf(v, h, l);
    inph[idx] = h; inpl[idx] = l;
  }
}

// ---------- LSTM cell body: tile M=128 batch x N=64 gate-cols (16 units x 4 gates) ----------
// bx in [0,128): unit tile = bx & 31 (XCD-affine), batch tile = bx >> 5.
// 256 thr = 4 waves (wm = wid>>1 selects M-half 64, wn = wid&1 selects N-half 32).
// Split-bf16: P ~= Xh@Wh + Xh@Wl + Xl@Wh via mfma_f32_32x32x16_bf16.
__device__ __forceinline__ void lstm_body(
    char* smem, int bx,
    const u16* __restrict__ Xh, const u16* __restrict__ Xl,   // split X (or null)
    const float* __restrict__ Xg, long xstride, int K1,       // guarded fp32 X (raw x_enc)
    int K1pad,
    const u16* __restrict__ Wih_h, const u16* __restrict__ Wih_l, // [2048][K1pad]
    const u16* __restrict__ Whh_h, const u16* __restrict__ Whh_l, // [2048][512]
    const float* __restrict__ bias,
    const u16* __restrict__ Hph, const u16* __restrict__ Hpl, // prev h split [512][512]
    u16* __restrict__ Hnh, u16* __restrict__ Hnl,             // next h split
    float* __restrict__ cst)                                  // c state fp32 [512][512]
{
  u16 (*sXh)[48] = (u16 (*)[48])(smem);
  u16 (*sXl)[48] = (u16 (*)[48])(smem + 12288);
  u16 (*sWh)[48] = (u16 (*)[48])(smem + 24576);
  u16 (*sWl)[48] = (u16 (*)[48])(smem + 30720);
  float (*sG)[68] = (float (*)[68])(smem);    // aliases staging; used only after final sync

  const int tid  = threadIdx.x;
  const int lane = tid & 63;
  const int wid  = tid >> 6;
  const int wm = wid >> 1, wn = wid & 1;
  const int m0 = (bx >> 5) * 128;
  const int u0 = (bx & 31) * 16;

  floatx16 acc0 = {0.f,0.f,0.f,0.f,0.f,0.f,0.f,0.f,0.f,0.f,0.f,0.f,0.f,0.f,0.f,0.f};
  floatx16 acc1 = {0.f,0.f,0.f,0.f,0.f,0.f,0.f,0.f,0.f,0.f,0.f,0.f,0.f,0.f,0.f,0.f};

  const int xr = tid >> 1;           // 0..127
  const int xc = (tid & 1) * 16;     // 0/16
  const int wr = tid >> 2;           // 0..63: gate = wr>>4, unit = wr&15
  const int wk = (tid & 3) * 8;      // 0,8,16,24
  const size_t grow = (size_t)((wr >> 4) * HH + u0 + (wr & 15));

  const int ml = lane & 31;
  const int kh = (lane >> 5) * 8;    // K-subslice

  const int nch1 = K1pad >> 5;
  const int ncht = nch1 + (HH >> 5);

  for (int ch = 0; ch < ncht; ++ch){
    const bool ph1 = ch < nch1;
    const int k0 = (ph1 ? ch : ch - nch1) << 5;

    // ---- stage X (128 x 32) ----
    if (ph1 && Xg){
      const float* src = Xg + (size_t)(m0 + xr) * xstride + k0 + xc;
      #pragma unroll
      for (int j = 0; j < 16; ++j){
        float v = (k0 + xc + j < K1) ? src[j] : 0.f;
        u16 h, l; splitf(v, h, l);
        sXh[xr][xc + j] = h; sXl[xr][xc + j] = l;
      }
    } else {
      const u16* bh_ = ph1 ? (Xh + (size_t)(m0 + xr) * K1pad + k0 + xc)
                           : (Hph + (size_t)(m0 + xr) * HH + k0 + xc);
      const u16* bl_ = ph1 ? (Xl + (size_t)(m0 + xr) * K1pad + k0 + xc)
                           : (Hpl + (size_t)(m0 + xr) * HH + k0 + xc);
      *(bf16x8*)&sXh[xr][xc]     = *(const bf16x8*)(bh_);
      *(bf16x8*)&sXh[xr][xc + 8] = *(const bf16x8*)(bh_ + 8);
      *(bf16x8*)&sXl[xr][xc]     = *(const bf16x8*)(bl_);
      *(bf16x8*)&sXl[xr][xc + 8] = *(const bf16x8*)(bl_ + 8);
    }
    // ---- stage W (64 x 32) ----
    {
      const u16* Wh = ph1 ? Wih_h : Whh_h;
      const u16* Wl = ph1 ? Wih_l : Whh_l;
      const size_t Kp = ph1 ? (size_t)K1pad : (size_t)HH;
      *(bf16x8*)&sWh[wr][wk] = *(const bf16x8*)(Wh + grow * Kp + k0 + wk);
      *(bf16x8*)&sWl[wr][wk] = *(const bf16x8*)(Wl + grow * Kp + k0 + wk);
    }
    __syncthreads();
    // ---- 12 MFMAs (2 k-halves x 2 M-tiles x 3 split products) ----
    #pragma unroll
    for (int kk = 0; kk < 32; kk += 16){
      bf16x8 ah0 = *(const bf16x8*)&sXh[wm * 64 + ml][kk + kh];
      bf16x8 al0 = *(const bf16x8*)&sXl[wm * 64 + ml][kk + kh];
      bf16x8 ah1 = *(const bf16x8*)&sXh[wm * 64 + 32 + ml][kk + kh];
      bf16x8 al1 = *(const bf16x8*)&sXl[wm * 64 + 32 + ml][kk + kh];
      bf16x8 bh  = *(const bf16x8*)&sWh[wn * 32 + ml][kk + kh];
      bf16x8 bl  = *(const bf16x8*)&sWl[wn * 32 + ml][kk + kh];
      acc0 = __builtin_amdgcn_mfma_f32_32x32x16_bf16(ah0, bh, acc0, 0, 0, 0);
      acc0 = __builtin_amdgcn_mfma_f32_32x32x16_bf16(ah0, bl, acc0, 0, 0, 0);
      acc0 = __builtin_amdgcn_mfma_f32_32x32x16_bf16(al0, bh, acc0, 0, 0, 0);
      acc1 = __builtin_amdgcn_mfma_f32_32x32x16_bf16(ah1, bh, acc1, 0, 0, 0);
      acc1 = __builtin_amdgcn_mfma_f32_32x32x16_bf16(ah1, bl, acc1, 0, 0, 0);
      acc1 = __builtin_amdgcn_mfma_f32_32x32x16_bf16(al1, bh, acc1, 0, 0, 0);
    }
    __syncthreads();
  }

  // ---- epilogue: gate exchange via LDS (aliased), cell update, split-write h ----
  #pragma unroll
  for (int r = 0; r < 16; ++r){
    const int mm = (r & 3) + 8 * (r >> 2) + (kh >> 1);  // C/D row: (reg&3)+8*(reg>>2)+4*(lane>>5)
    sG[wm * 64 + mm][wn * 32 + ml]      = acc0[r];
    sG[wm * 64 + 32 + mm][wn * 32 + ml] = acc1[r];
  }
  __syncthreads();
  for (int e = tid; e < 2048; e += 256){
    const int m = e >> 4, u = e & 15;
    const int gj = u0 + u;
    const float gi = sG[m][u]      + bias[gj];
    const float gf = sG[m][16 + u] + bias[HH + gj];
    const float gg = sG[m][32 + u] + bias[2 * HH + gj];
    const float go = sG[m][48 + u] + bias[3 * HH + gj];
    const float si = 1.f / (1.f + expf(-gi));
    const float sf = 1.f / (1.f + expf(-gf));
    const float so = 1.f / (1.f + expf(-go));
    const size_t sidx = (size_t)(m0 + m) * HH + gj;
    const float cn = sf * cst[sidx] + si * tanhf(gg);
    const float hn = so * tanhf(cn);
    cst[sidx] = cn;
    u16 hh, hl; splitf(hn, hh, hl);
    Hnh[sidx] = hh; Hnl[sidx] = hl;
  }
}

__global__ __launch_bounds__(256) void lstm_one(
    const u16* Xh, const u16* Xl, int K1pad,
    const u16* Wih_h, const u16* Wih_l, const u16* Whh_h, const u16* Whh_l,
    const float* bias, const u16* Hph, const u16* Hpl,
    u16* Hnh, u16* Hnl, float* cst)
{
  extern __shared__ char smem[];
  lstm_body(smem, blockIdx.x, Xh, Xl, nullptr, 0, 0, K1pad,
            Wih_h, Wih_l, Whh_h, Whh_l, bias, Hph, Hpl, Hnh, Hnl, cst);
}

// Fused encoder step: blocks [0,128) = cell0 step t (raw x_enc), [128,256) = cell1 step t-1.
// Single lstm_body call site; operands selected per half.
__global__ __launch_bounds__(256) void lstm_pair(
    int act0, const float* xg, long xstride,
    const u16* W0ih_h, const u16* W0ih_l, const u16* W0hh_h, const u16* W0hh_l,
    const float* b0, const u16* H0ph, const u16* H0pl, u16* H0nh, u16* H0nl, float* c0,
    int act1, const u16* X1h, const u16* X1l,
    const u16* W1ih_h, const u16* W1ih_l, const u16* W1hh_h, const u16* W1hh_l,
    const float* b1, const u16* H1ph, const u16* H1pl, u16* H1nh, u16* H1nl, float* c1)
{
  extern __shared__ char smem[];
  const int half = blockIdx.x >> 7;
  const int bx   = blockIdx.x & 127;
  if (half == 0 ? !act0 : !act1) return;
  const u16* Xh = half ? X1h : nullptr;
  const u16* Xl = half ? X1l : nullptr;
  const float* Xg = half ? nullptr : xg;
  const long xs = half ? 0 : xstride;
  const int K1 = half ? 0 : EE;
  const int K1pad = half ? HH : EPAD;
  lstm_body(smem, bx, Xh, Xl, Xg, xs, K1, K1pad,
            half ? W1ih_h : W0ih_h, half ? W1ih_l : W0ih_l,
            half ? W1hh_h : W0hh_h, half ? W1hh_l : W0hh_l,
            half ? b1 : b0,
            half ? H1ph : H0ph, half ? H1pl : H0pl,
            half ? H1nh : H0nh, half ? H1nl : H0nl,
            half ? c1 : c0);
}

// ---------- FC head (split-bf16 MFMA): out = h1 @ fcW^T + fcb ----------
// grid (4, 6): M=128 batch x N=64 out-cols; direct register epilogue.
__global__ __launch_bounds__(256) void fc_mfma(
    const u16* __restrict__ Hh, const u16* __restrict__ Hl,       // [512][512]
    const u16* __restrict__ Wh, const u16* __restrict__ Wl,       // [384][512]
    const float* __restrict__ bfc,                                // [384]
    float* __restrict__ out, u16* __restrict__ inph, u16* __restrict__ inpl, int p)
{
  __shared__ u16 sXh[128][48], sXl[128][48], sWh[64][48], sWl[64][48];
  const int tid = threadIdx.x, lane = tid & 63, wid = tid >> 6;
  const int wm = wid >> 1, wn = wid & 1;
  const int m0 = blockIdx.x * 128;
  const int n0 = blockIdx.y * 64;

  floatx16 acc0 = {0.f,0.f,0.f,0.f,0.f,0.f,0.f,0.f,0.f,0.f,0.f,0.f,0.f,0.f,0.f,0.f};
  floatx16 acc1 = {0.f,0.f,0.f,0.f,0.f,0.f,0.f,0.f,0.f,0.f,0.f,0.f,0.f,0.f,0.f,0.f};

  const int xr = tid >> 1, xc = (tid & 1) * 16;
  const int wr = tid >> 2, wk = (tid & 3) * 8;
  const int ml = lane & 31, kh = (lane >> 5) * 8;

  for (int ch = 0; ch < 16; ++ch){
    const int k0 = ch << 5;
    {
      const u16* bh_ = Hh + (size_t)(m0 + xr) * HH + k0 + xc;
      const u16* bl_ = Hl + (size_t)(m0 + xr) * HH + k0 + xc;
      *(bf16x8*)&sXh[xr][xc]     = *(const bf16x8*)(bh_);
      *(bf16x8*)&sXh[xr][xc + 8] = *(const bf16x8*)(bh_ + 8);
      *(bf16x8*)&sXl[xr][xc]     = *(const bf16x8*)(bl_);
      *(bf16x8*)&sXl[xr][xc + 8] = *(const bf16x8*)(bl_ + 8);
    }
    *(bf16x8*)&sWh[wr][wk] = *(const bf16x8*)(Wh + (size_t)(n0 + wr) * HH + k0 + wk);
    *(bf16x8*)&sWl[wr][wk] = *(const bf16x8*)(Wl + (size_t)(n0 + wr) * HH + k0 + wk);
    __syncthreads();
    #pragma unroll
    for (int kk = 0; kk < 32; kk += 16){
      bf16x8 ah0 = *(const bf16x8*)&sXh[wm * 64 + ml][kk + kh];
      bf16x8 al0 = *(const bf16x8*)&sXl[wm * 64 + ml][kk + kh];
      bf16x8 ah1 = *(const bf16x8*)&sXh[wm * 64 + 32 + ml][kk + kh];
      bf16x8 al1 = *(const bf16x8*)&sXl[wm * 64 + 32 + ml][kk + kh];
      bf16x8 bh  = *(const bf16x8*)&sWh[wn * 32 + ml][kk + kh];
      bf16x8 bl  = *(const bf16x8*)&sWl[wn * 32 + ml][kk + kh];
      acc0 = __builtin_amdgcn_mfma_f32_32x32x16_bf16(ah0, bh, acc0, 0, 0, 0);
      acc0 = __builtin_amdgcn_mfma_f32_32x32x16_bf16(ah0, bl, acc0, 0, 0, 0);
      acc0 = __builtin_amdgcn_mfma_f32_32x32x16_bf16(al0, bh, acc0, 0, 0, 0);
      acc1 = __builtin_amdgcn_mfma_f32_32x32x16_bf16(ah1, bh, acc1, 0, 0, 0);
      acc1 = __builtin_amdgcn_mfma_f32_32x32x16_bf16(ah1, bl, acc1, 0, 0, 0);
      acc1 = __builtin_amdgcn_mfma_f32_32x32x16_bf16(al1, bh, acc1, 0, 0, 0);
    }
    __syncthreads();
  }
  const int n = n0 + wn * 32 + ml;
  if (n < CC){
    const float bv = bfc[n];
    #pragma unroll
    for (int r = 0; r < 16; ++r){
      const int mm = (r & 3) + 8 * (r >> 2) + (kh >> 1);
      {
        const int b = m0 + wm * 64 + mm;
        const float v = acc0[r] + bv;
        out[(size_t)b * PP * CC + (size_t)p * CC + n] = v;
        u16 hh, hl; splitf(v, hh, hl);
        inph[(size_t)b * EPAD + n] = hh; inpl[(size_t)b * EPAD + n] = hl;
      }
      {
        const int b = m0 + wm * 64 + 32 + mm;
        const float v = acc1[r] + bv;
        out[(size_t)b * PP * CC + (size_t)p * CC + n] = v;
        u16 hh, hl; splitf(v, hh, hl);
        inph[(size_t)b * EPAD + n] = hh; inpl[(size_t)b * EPAD + n] = hl;
      }
    }
  }
}

extern "C" void kernel_launch(void* const* d_in, const int* in_sizes, int n_in,
                              void* d_out, int out_size, void* d_ws, size_t ws_size,
                              hipStream_t stream) {
  const float* x_enc  = (const float*)d_in[0];
  const float* e_Wih0 = (const float*)d_in[4];
  const float* e_Whh0 = (const float*)d_in[5];
  const float* e_bih0 = (const float*)d_in[6];
  const float* e_bhh0 = (const float*)d_in[7];
  const float* e_Wih1 = (const float*)d_in[8];
  const float* e_Whh1 = (const float*)d_in[9];
  const float* e_bih1 = (const float*)d_in[10];
  const float* e_bhh1 = (const float*)d_in[11];
  const float* d_Wih0 = (const float*)d_in[12];
  const float* d_Whh0 = (const float*)d_in[13];
  const float* d_bih0 = (const float*)d_in[14];
  const float* d_bhh0 = (const float*)d_in[15];
  const float* d_Wih1 = (const float*)d_in[16];
  const float* d_Whh1 = (const float*)d_in[17];
  const float* d_bih1 = (const float*)d_in[18];
  const float* d_bhh1 = (const float*)d_in[19];
  const float* fc_W   = (const float*)d_in[20];
  const float* fc_b   = (const float*)d_in[21];

  char* base = (char*)d_ws;
  size_t off = 0;
  auto alloc_us = [&](size_t n){ u16* p = (u16*)(base + off); off += ((n * 2 + 15) & ~(size_t)15); return p; };
  auto alloc_f  = [&](size_t n){ float* p = (float*)(base + off); off += ((n * 4 + 15) & ~(size_t)15); return p; };

  u16 *We0ih_h = alloc_us((size_t)G4 * EPAD), *We0ih_l = alloc_us((size_t)G4 * EPAD);
  u16 *We0hh_h = alloc_us((size_t)G4 * HH),   *We0hh_l = alloc_us((size_t)G4 * HH);
  u16 *We1ih_h = alloc_us((size_t)G4 * HH),   *We1ih_l = alloc_us((size_t)G4 * HH);
  u16 *We1hh_h = alloc_us((size_t)G4 * HH),   *We1hh_l = alloc_us((size_t)G4 * HH);
  u16 *Wd0ih_h = alloc_us((size_t)G4 * EPAD), *Wd0ih_l = alloc_us((size_t)G4 * EPAD);
  u16 *Wd0hh_h = alloc_us((size_t)G4 * HH),   *Wd0hh_l = alloc_us((size_t)G4 * HH);
  u16 *Wd1ih_h = alloc_us((size_t)G4 * HH),   *Wd1ih_l = alloc_us((size_t)G4 * HH);
  u16 *Wd1hh_h = alloc_us((size_t)G4 * HH),   *Wd1hh_l = alloc_us((size_t)G4 * HH);
  u16 *Wfc_h   = alloc_us((size_t)NFC * HH),  *Wfc_l   = alloc_us((size_t)NFC * HH);
  float* be0 = alloc_f(G4);
  float* be1 = alloc_f(G4);
  float* bd0 = alloc_f(G4);
  float* bd1 = alloc_f(G4);
  float* bfc = alloc_f(NFC);
  // zero-init region: h0[0], h1[0] (hi+lo) then c0, c1 — one memset covers all
  u16* h0h[2]; u16* h0l[2]; u16* h1h[2]; u16* h1l[2];
  h0h[0] = alloc_us((size_t)BB * HH); h0l[0] = alloc_us((size_t)BB * HH);
  h1h[0] = alloc_us((size_t)BB * HH); h1l[0] = alloc_us((size_t)BB * HH);
  float* c0 = alloc_f((size_t)BB * HH);
  float* c1 = alloc_f((size_t)BB * HH);
  h0h[1] = alloc_us((size_t)BB * HH); h0l[1] = alloc_us((size_t)BB * HH);
  h1h[1] = alloc_us((size_t)BB * HH); h1l[1] = alloc_us((size_t)BB * HH);
  u16* inph = alloc_us((size_t)BB * EPAD);
  u16* inpl = alloc_us((size_t)BB * EPAD);

  // prep (every launch; ws re-poisoned by harness)
  cvt_split<<<512, 256, 0, stream>>>(e_Wih0, We0ih_h, We0ih_l, G4, EE, G4, EPAD);
  cvt_split<<<512, 256, 0, stream>>>(e_Whh0, We0hh_h, We0hh_l, G4, HH, G4, HH);
  cvt_split<<<512, 256, 0, stream>>>(e_Wih1, We1ih_h, We1ih_l, G4, HH, G4, HH);
  cvt_split<<<512, 256, 0, stream>>>(e_Whh1, We1hh_h, We1hh_l, G4, HH, G4, HH);
  cvt_split<<<512, 256, 0, stream>>>(d_Wih0, Wd0ih_h, Wd0ih_l, G4, EE, G4, EPAD);
  cvt_split<<<512, 256, 0, stream>>>(d_Whh0, Wd0hh_h, Wd0hh_l, G4, HH, G4, HH);
  cvt_split<<<512, 256, 0, stream>>>(d_Wih1, Wd1ih_h, Wd1ih_l, G4, HH, G4, HH);
  cvt_split<<<512, 256, 0, stream>>>(d_Whh1, Wd1hh_h, Wd1hh_l, G4, HH, G4, HH);
  cvt_split<<<512, 256, 0, stream>>>(fc_W,   Wfc_h,   Wfc_l,   CC, HH, NFC, HH);
  cvt_bias<<<8, 256, 0, stream>>>(e_bih0, e_bhh0, be0, G4, G4);
  cvt_bias<<<8, 256, 0, stream>>>(e_bih1, e_bhh1, be1, G4, G4);
  cvt_bias<<<8, 256, 0, stream>>>(d_bih0, d_bhh0, bd0, G4, G4);
  cvt_bias<<<8, 256, 0, stream>>>(d_bih1, d_bhh1, bd1, G4, G4);
  cvt_bias<<<2, 256, 0, stream>>>(fc_b, nullptr, bfc, CC, NFC);
  hipMemsetAsync(h0h[0], 0, (size_t)4 * BB * HH * sizeof(u16) + (size_t)2 * BB * HH * sizeof(float), stream);
  init_inp<<<512, 256, 0, stream>>>(x_enc, inph, inpl);

  // encoder: fused pipeline, iteration t runs cell0(t) and cell1(t-1)
  for (int t = 0; t <= TT; ++t){
    const int rd = t & 1, wrp = (t + 1) & 1;
    lstm_pair<<<256, 256, LSTM_SMEM, stream>>>(
        (t < TT) ? 1 : 0, x_enc + (size_t)t * EE, (long)TT * EE,
        We0ih_h, We0ih_l, We0hh_h, We0hh_l, be0,
        h0h[rd], h0l[rd], h0h[wrp], h0l[wrp], c0,
        (t > 0) ? 1 : 0, h0h[rd], h0l[rd],
        We1ih_h, We1ih_l, We1hh_h, We1hh_l, be1,
        h1h[wrp], h1l[wrp], h1h[rd], h1l[rd], c1);
  }
  // encoder finals land at parity 0 for both h0 and h1

  // decoder
  float* out = (float*)d_out;
  for (int p = 0; p < PP; ++p){
    const int rd = p & 1, wrp = (p + 1) & 1;
    lstm_one<<<128, 256, LSTM_SMEM, stream>>>(
        inph, inpl, EPAD,
        Wd0ih_h, Wd0ih_l, Wd0hh_h, Wd0hh_l, bd0,
        h0h[rd], h0l[rd], h0h[wrp], h0l[wrp], c0);
    lstm_one<<<128, 256, LSTM_SMEM, stream>>>(
        h0h[wrp], h0l[wrp], HH,
        Wd1ih_h, Wd1ih_l, Wd1hh_h, Wd1hh_l, bd1,
        h1h[rd], h1l[rd], h1h[wrp], h1l[wrp], c1);
    fc_mfma<<<dim3(4, 6), 256, 0, stream>>>(
        h1h[wrp], h1l[wrp], Wfc_h, Wfc_l, bfc, out, inph, inpl, p);
  }
}